// Round 1
// 4364.337 us; speedup vs baseline: 1.0548x; 1.0548x over previous
//
#include <hip/hip_runtime.h>
#include <hip/hip_fp16.h>

#define BB 128
#define II 64
#define SS 2048
#define HH 128
#define GG 512   // 4*H
#define OO 64
#define TT 32    // x time-tile width

typedef _Float16 f16x2 __attribute__((ext_vector_type(2)));
union F4H { float4 f4; f16x2 h[4]; };

__device__ __forceinline__ f16x2 pack2(float a, float b) {
    f16x2 r; r.x = (_Float16)a; r.y = (_Float16)b; return r;
}

__device__ __forceinline__ float dot2(f16x2 w, f16x2 v, float c) {
#if __has_builtin(__builtin_amdgcn_fdot2)
    return __builtin_amdgcn_fdot2(w, v, c, false);
#else
    return fmaf((float)w.x, (float)v.x, fmaf((float)w.y, (float)v.y, c));
#endif
}

__device__ __forceinline__ float sigm(float v) {
    return __builtin_amdgcn_rcpf(1.0f + __expf(-v));
}
__device__ __forceinline__ float tanh_f(float v) {
    float a = fabsf(v);
    float e = __expf(-2.0f * a);
    float r = (1.0f - e) * __builtin_amdgcn_rcpf(1.0f + e);
    return v < 0.0f ? -r : r;
}

// One block per batch element, 512 threads, thread j owns gate column j.
// Wh_out, Wx_in, Wh_in fp16 in registers (192 VGPRs) -> REQUIRES a 256-VGPR
// budget. __launch_bounds__(512[,2]) and single-arg amdgpu_waves_per_eu(2)
// both left the allocator at 128 (measured VGPR_Count=128 -> partial spill).
// Pin min AND max waves/EU to 2 with no __launch_bounds__: budget = 512/2 = 256.
__global__ void
__attribute__((amdgpu_flat_work_group_size(512, 512)))
__attribute__((amdgpu_waves_per_eu(2, 2)))
nlstm_scan(
    const float* __restrict__ x,
    const float* __restrict__ Wx_out, const float* __restrict__ Wh_out,
    const float* __restrict__ b_out,
    const float* __restrict__ Wx_in, const float* __restrict__ Wh_in,
    const float* __restrict__ b_in,
    const float* __restrict__ W_lin, const float* __restrict__ b_lin,
    float* __restrict__ out)
{
    const int b = blockIdx.x;
    const int j = threadIdx.x;

    // Wx_out fp16, chunk-major: chunk c (k=8c..8c+8) of column j at wxf[c*512+j].
    __shared__ __align__(16) float4 wxf[8 * 512];          // 64 KB
    // W_lin fp16, chunk-major padded: chunk c of row pn at wlf[c*66+pn].
    __shared__ __align__(16) float4 wlf[16 * 66];          // 16.5 KB
    // x time-tile, double-buffered, +1 pad breaks the column-read bank conflict.
    __shared__ float xt[2][II][TT + 1];                    // 16.9 KB
    __shared__ __align__(16) f16x2 xb[2][II / 2];          // x_t fp16, dbuf
    __shared__ __align__(16) f16x2 hb[HH / 2];             // h fp16
    __shared__ __align__(16) f16x2 xib[HH / 2];            // x_in fp16
    __shared__ __align__(16) f16x2 hib[HH / 2];            // h_in fp16
    __shared__ float cb[HH];                               // outer cell fp32
    __shared__ float cnb[HH];                              // inner cell fp32
    __shared__ float actO[GG];
    __shared__ float actI[GG];

    // ---- register-resident fp16 weights (column j) : 192 VGPRs ----
    f16x2 who[HH / 2];   // Wh_out col j
    f16x2 wxi[HH / 2];   // Wx_in  col j
    f16x2 whi[HH / 2];   // Wh_in  col j
#pragma unroll
    for (int m = 0; m < HH / 2; ++m)
        who[m] = pack2(Wh_out[(2 * m) * GG + j], Wh_out[(2 * m + 1) * GG + j]);
#pragma unroll
    for (int m = 0; m < HH / 2; ++m)
        wxi[m] = pack2(Wx_in[(2 * m) * GG + j], Wx_in[(2 * m + 1) * GG + j]);
#pragma unroll
    for (int m = 0; m < HH / 2; ++m)
        whi[m] = pack2(Wh_in[(2 * m) * GG + j], Wh_in[(2 * m + 1) * GG + j]);

    const float bo = b_out[j];
    const float bi = b_in[j];
    const int   pn = j >> 3;
    const int   ps = j & 7;
    const float bl = b_lin[pn];

    // Wx_out -> LDS fp16 (thread j converts its own column)
#pragma unroll
    for (int c = 0; c < 8; ++c) {
        F4H u;
#pragma unroll
        for (int q = 0; q < 4; ++q)
            u.h[q] = pack2(Wx_out[(8 * c + 2 * q) * GG + j],
                           Wx_out[(8 * c + 2 * q + 1) * GG + j]);
        wxf[c * 512 + j] = u.f4;
    }
    // W_lin -> LDS fp16 (1024 chunks, 2 per thread)
#pragma unroll
    for (int r = 0; r < 2; ++r) {
        const int m = r * 512 + j;
        const int c = m >> 6, n = m & 63;
        F4H u;
#pragma unroll
        for (int q = 0; q < 4; ++q)
            u.h[q] = pack2(W_lin[n * HH + 8 * c + 2 * q],
                           W_lin[n * HH + 8 * c + 2 * q + 1]);
        wlf[c * 66 + n] = u.f4;
    }

    const float* xrow = x + (size_t)b * II * SS;   // x[b,i,t] = xrow[i*SS + t]
    float* orow = out + (size_t)b * SS * OO;

    // tile 0 -> xt[0]: thread j loads x[b, j>>3, 4*(j&7) .. +3] (coalesced)
    {
        const int row = j >> 3, tc = j & 7;
        const float4 v = *(const float4*)(xrow + (size_t)row * SS + 4 * tc);
        float* dst = &xt[0][row][4 * tc];
        dst[0] = v.x; dst[1] = v.y; dst[2] = v.z; dst[3] = v.w;
    }
    if (j < HH / 2) hb[j] = pack2(0.f, 0.f);
    if (j < HH) { cb[j] = 0.f; cnb[j] = 0.f; }
    if (j >= 256 && j < 256 + 32) {                // initial xb[0] pack (t=0)
        const int m = j - 256;
        xb[0][m] = pack2(xrow[(2 * m) * SS], xrow[(2 * m + 1) * SS]);
    }
    __syncthreads();

    const float4* hb4 = (const float4*)hb;   // 16 chunks
    const float4* xi4 = (const float4*)xib;
    const float4* hi4 = (const float4*)hib;

#pragma unroll 1
    for (int t = 0; t < SS; ++t) {
        // ---- phase A: outer gates, col j of xt@Wx_out + h@Wh_out + b ----
        // (reads xb[t&1]/hb written before B5 of step t-1 -> no extra barrier)
        const float4* xcur = (const float4*)xb[t & 1];
        float a0 = bo, a1 = 0.f, a2 = 0.f, a3 = 0.f;
#pragma unroll
        for (int c = 0; c < 8; ++c) {
            F4H xu; xu.f4 = xcur[c];
            F4H wu; wu.f4 = wxf[c * 512 + j];
            a0 = dot2(wu.h[0], xu.h[0], a0);
            a1 = dot2(wu.h[1], xu.h[1], a1);
            a2 = dot2(wu.h[2], xu.h[2], a2);
            a3 = dot2(wu.h[3], xu.h[3], a3);
        }
#pragma unroll
        for (int c = 0; c < 16; ++c) {
            F4H hu; hu.f4 = hb4[c];
            a0 = dot2(who[4 * c + 0], hu.h[0], a0);
            a1 = dot2(who[4 * c + 1], hu.h[1], a1);
            a2 = dot2(who[4 * c + 2], hu.h[2], a2);
            a3 = dot2(who[4 * c + 3], hu.h[3], a3);
        }
        {
            const float acc = (a0 + a1) + (a2 + a3);
            actO[j] = (j < 384) ? sigm(acc) : tanh_f(acc);
        }
        __syncthreads();   // B2

        // ---- phase B: inner-LSTM inputs ----
        if (j < II) {  // x_in pairs
            xib[j] = pack2(actO[2 * j] * actO[384 + 2 * j],
                           actO[2 * j + 1] * actO[384 + 2 * j + 1]);
        } else if (j < II + HH / 2) {  // h_in pairs
            const int m = j - II;
            hib[m] = pack2(actO[HH + 2 * m] * cb[2 * m],
                           actO[HH + 2 * m + 1] * cb[2 * m + 1]);
        }
        __syncthreads();   // B3

        // ---- phase C: inner gates ----
        float c0 = bi, c1 = 0.f, c2 = 0.f, c3 = 0.f;
#pragma unroll
        for (int c = 0; c < 16; ++c) {
            F4H xu; xu.f4 = xi4[c];
            c0 = dot2(wxi[4 * c + 0], xu.h[0], c0);
            c1 = dot2(wxi[4 * c + 1], xu.h[1], c1);
            c2 = dot2(wxi[4 * c + 2], xu.h[2], c2);
            c3 = dot2(wxi[4 * c + 3], xu.h[3], c3);
        }
#pragma unroll
        for (int c = 0; c < 16; ++c) {
            F4H hu; hu.f4 = hi4[c];
            c0 = dot2(whi[4 * c + 0], hu.h[0], c0);
            c1 = dot2(whi[4 * c + 1], hu.h[1], c1);
            c2 = dot2(whi[4 * c + 2], hu.h[2], c2);
            c3 = dot2(whi[4 * c + 3], hu.h[3], c3);
        }
        {
            const float acc2 = (c0 + c1) + (c2 + c3);
            actI[j] = (j < 384) ? sigm(acc2) : tanh_f(acc2);
        }
        __syncthreads();   // B4

        // ---- phase D: state update + x staging for t+1 / tile prefetch ----
        // Tile T'=(t+2)>>5 is loaded at (t&31)==30 into the buffer that the
        // pack at step t+1 (which crosses into tile T') reads AFTER B5(t).
        const bool doTile = ((t & 31) == 30) && (t + 2 < SS);
        float4 xld; int Tn = 0;
        if (doTile) {
            Tn = (t + 2) >> 5;
            const int row = j >> 3, tc = j & 7;
            xld = *(const float4*)(xrow + (size_t)row * SS + TT * Tn + 4 * tc);
        }
        if (j < HH) {
            const float cn_new = actI[HH + j] * cnb[j] + actI[j] * actI[384 + j];
            const float c_new  = actI[2 * HH + j] * tanh_f(cn_new);
            const float h_new  = actO[2 * HH + j] * tanh_f(c_new);
            cnb[j] = cn_new;
            cb[j]  = c_new;
            ((_Float16*)hb)[j] = (_Float16)h_new;
        } else if (j < HH + 32) {   // pack xb for t+1 from the LDS tile
            const int m = j - HH;
            const int tn = t + 1;   // tn==SS reads stale LDS, result unused
            const int tbn = (tn >> 5) & 1, ttn = tn & 31;
            xb[tn & 1][m] = pack2(xt[tbn][2 * m][ttn],
                                  xt[tbn][2 * m + 1][ttn]);
        }
        if (doTile) {
            const int row = j >> 3, tc = j & 7;
            float* dst = &xt[Tn & 1][row][4 * tc];
            dst[0] = xld.x; dst[1] = xld.y; dst[2] = xld.z; dst[3] = xld.w;
        }
        __syncthreads();   // B5

        // ---- phase E: fused projection (shares interval with next phase A) ----
        float p = 0.f;
#pragma unroll
        for (int q = 0; q < 2; ++q) {
            const int c = 2 * ps + q;
            F4H hu; hu.f4 = hb4[c];
            F4H wu; wu.f4 = wlf[c * 66 + pn];
            p = dot2(wu.h[0], hu.h[0], p);
            p = dot2(wu.h[1], hu.h[1], p);
            p = dot2(wu.h[2], hu.h[2], p);
            p = dot2(wu.h[3], hu.h[3], p);
        }
        p += __shfl_down(p, 4, 8);
        p += __shfl_down(p, 2, 8);
        p += __shfl_down(p, 1, 8);
        if (ps == 0) orow[t * OO + pn] = p + bl;
    }
}

extern "C" void kernel_launch(void* const* d_in, const int* in_sizes, int n_in,
                              void* d_out, int out_size, void* d_ws, size_t ws_size,
                              hipStream_t stream) {
    (void)in_sizes; (void)n_in; (void)d_ws; (void)ws_size; (void)out_size;
    const float* x      = (const float*)d_in[0];
    const float* Wx_out = (const float*)d_in[1];
    const float* Wh_out = (const float*)d_in[2];
    const float* b_out  = (const float*)d_in[3];
    const float* Wx_in  = (const float*)d_in[4];
    const float* Wh_in  = (const float*)d_in[5];
    const float* b_in   = (const float*)d_in[6];
    const float* W_lin  = (const float*)d_in[7];
    const float* b_lin  = (const float*)d_in[8];
    float* out = (float*)d_out;

    nlstm_scan<<<dim3(BB), dim3(512), 0, stream>>>(
        x, Wx_out, Wh_out, b_out, Wx_in, Wh_in, b_in, W_lin, b_lin, out);
}